// Round 5
// baseline (451.046 us; speedup 1.0000x reference)
//
#include <hip/hip_runtime.h>
#include <math.h>
#include <stdint.h>

namespace {

constexpr int T = 50;
constexpr int NB = 32768;
constexpr int H = 128;
constexpr int NTHREADS = 256;   // 4 waves; each wave owns 32 N-cols (2 n-tiles)
constexpr int BLK_ROWS = 32;    // rows per block; all 4 waves cooperate on them

typedef float v4f __attribute__((ext_vector_type(4)));
typedef float v2f __attribute__((ext_vector_type(2)));
typedef unsigned int v4u __attribute__((ext_vector_type(4)));
typedef short short8 __attribute__((ext_vector_type(8)));

union FU { float f; uint32_t u; };
union U8 { uint32_t u[4]; short8 v; };

__device__ __forceinline__ uint32_t pack_hi16(uint32_t odd, uint32_t even) {
  return (odd & 0xFFFF0000u) | (even >> 16);
}
__device__ __forceinline__ uint32_t pack_lo16(uint32_t odd, uint32_t even) {
  return (odd << 16) | (even & 0xFFFFu);
}

// 2-way bf16 split: a ~= bf16(hi)+bf16(mid), residual <= 2^-16 |a|
__device__ __forceinline__ void split2(float a, uint32_t& hi, uint32_t& mid) {
  FU c0; c0.f = a;
  uint32_t uh = c0.u & 0xFFFF0000u;
  FU fh; fh.u = uh;
  float r1 = a - fh.f;   // exact
  FU c1; c1.f = r1;
  hi = uh; mid = c1.u & 0xFFFF0000u;
}
// 3-way exact bf16 split
__device__ __forceinline__ void split3(float a, uint32_t& hi, uint32_t& mid, uint32_t& lo) {
  FU c0; c0.f = a;
  uint32_t uh = c0.u & 0xFFFF0000u;
  FU fh; fh.u = uh;
  float r1 = a - fh.f;
  FU c1; c1.f = r1;
  uint32_t um = c1.u & 0xFFFF0000u;
  FU fm; fm.u = um;
  float r2 = r1 - fm.f;
  FU c2; c2.f = r2;
  hi = uh; mid = um; lo = c2.u;
}

__device__ __forceinline__ v4f mfma16(short8 a, short8 b, v4f c) {
  return __builtin_amdgcn_mfma_f32_16x16x32_bf16(a, b, c, 0, 0, 0);
}

// build a frag from 8 top16-valued u32s
__device__ __forceinline__ short8 pack8(const uint32_t* w) {
  U8 f;
#pragma unroll
  for (int d = 0; d < 4; ++d) f.u[d] = pack_hi16(w[2*d+1], w[2*d]);
  return f.v;
}

// sum over the 16 lanes of a DPP row via rotations (VALU, not DS pipe)
template <int CTRL>
__device__ __forceinline__ float ror_add(float x) {
  FU a; a.f = x;
  int r = __builtin_amdgcn_update_dpp(0, (int)a.u, CTRL, 0xF, 0xF, false);
  FU b; b.u = (uint32_t)r;
  return x + b.f;
}
__device__ __forceinline__ float row_sum16(float x) {
  x = ror_add<0x128>(x);  // row_ror:8
  x = ror_add<0x124>(x);  // row_ror:4
  x = ror_add<0x122>(x);  // row_ror:2
  x = ror_add<0x121>(x);  // row_ror:1
  return x;
}

__global__ __launch_bounds__(NTHREADS, 2)
void fwdsim5(const float* __restrict__ proj,   // (B, 64)
             const float* __restrict__ idm,    // (B, T, 12)
             const float* __restrict__ merg,   // (B, T, 3)
             const float* __restrict__ W1,     // (73, 128)
             const float* __restrict__ b1,     // (128)
             const float* __restrict__ W2,     // (128, 128)
             const float* __restrict__ b2,     // (128)
             const float* __restrict__ W3,     // (128, 1)
             const float* __restrict__ b3,     // (1)
             const float* __restrict__ smean,  // (6)
             const float* __restrict__ svar,   // (6)
             float* __restrict__ out)          // (B, T)
{
  // h slice, hi16|mi16 packed: [row(32)][col(128) + pad4]
  __shared__ uint32_t sHc[32 * 132];   // 16896 B
  // per-wave layer-3 partials: [row(32)][wave(4)]
  __shared__ float actP[32 * 4];       // 512 B

  const int tid  = threadIdx.x;
  const int wave = tid >> 6;
  const int lane = tid & 63;
  const int gq   = lane >> 4;   // 0..3
  const int o    = lane & 15;   // 0..15
  const int row0 = blockIdx.x * BLK_ROWS;

  // this wave's two N columns for this lane
  const int n0 = wave * 32 + o;
  const int n1 = n0 + 16;

  // ---- scalars ----
  float mean[6], istd[6];
#pragma unroll
  for (int c = 0; c < 6; ++c) { mean[c] = smean[c]; istd[c] = 1.0f / sqrtf(svar[c]); }
  const float b3v  = b3[0];
  const float b2c0 = b2[n0], b2c1 = b2[n1];
  const float w3c0 = W3[n0], w3c1 = W3[n1];

  // ---- env B-frags (W1 rows 64..72, K zero-padded to 32) in registers ----
  short8 envh[2], envm[2];
#pragma unroll
  for (int ntl = 0; ntl < 2; ++ntl) {
    const int n = ntl ? n1 : n0;
    uint32_t hi[8], mi[8];
#pragma unroll
    for (int j = 0; j < 8; ++j) {
      const int k = gq * 8 + j;
      const float w = (k < 9) ? W1[(64 + k) * H + n] : 0.f;
      split2(w, hi[j], mi[j]);
    }
    envh[ntl] = pack8(hi);
    envm[ntl] = pack8(mi);
  }

  // ---- W2 B-frags for this wave's N-slice: [kt*2+ntl], 2 planes = 64 regs ----
  short8 w2h[8], w2m[8];
#pragma unroll
  for (int kt = 0; kt < 4; ++kt)
#pragma unroll
    for (int ntl = 0; ntl < 2; ++ntl) {
      const int n = ntl ? n1 : n0;
      uint32_t hi[8], mi[8];
#pragma unroll
      for (int j = 0; j < 8; ++j) split2(W2[(kt * 32 + gq * 8 + j) * H + n], hi[j], mi[j]);
      w2h[kt * 2 + ntl] = pack8(hi);
      w2m[kt * 2 + ntl] = pack8(mi);
    }

  // ---- base1 = b1 + proj @ W1[0:64] via 6-term exact-split MFMA (C layout) ----
  v4f base[2][2];   // [mt][ntl]: rows 16mt+4gq+r, col n(ntl)
#pragma unroll
  for (int mt = 0; mt < 2; ++mt) {
    base[mt][0] = (v4f){b2c0 * 0.f + b1[n0], b1[n0], b1[n0], b1[n0]};
    base[mt][1] = (v4f){b1[n1], b1[n1], b1[n1], b1[n1]};
    base[mt][0][0] = b1[n0];
  }
#pragma unroll
  for (int kt2 = 0; kt2 < 2; ++kt2) {
    short8 bh[2], bm[2], bl[2];
#pragma unroll
    for (int ntl = 0; ntl < 2; ++ntl) {
      const int n = ntl ? n1 : n0;
      uint32_t hi[8], mi[8], lo[8];
#pragma unroll
      for (int j = 0; j < 8; ++j) split3(W1[(kt2 * 32 + gq * 8 + j) * H + n], hi[j], mi[j], lo[j]);
      bh[ntl] = pack8(hi); bm[ntl] = pack8(mi); bl[ntl] = pack8(lo);
    }
#pragma unroll
    for (int mt = 0; mt < 2; ++mt) {
      const float* pp = proj + (size_t)(row0 + mt * 16 + o) * 64 + kt2 * 32 + gq * 8;
      v4f p0 = *(const v4f*)pp;
      v4f p1 = *(const v4f*)(pp + 4);
      uint32_t hi[8], mi[8], lo[8];
#pragma unroll
      for (int e = 0; e < 4; ++e) split3(p0[e], hi[e],   mi[e],   lo[e]);
#pragma unroll
      for (int e = 0; e < 4; ++e) split3(p1[e], hi[4+e], mi[4+e], lo[4+e]);
      short8 pah = pack8(hi), pam = pack8(mi), pal = pack8(lo);
#pragma unroll
      for (int ntl = 0; ntl < 2; ++ntl) {
        v4f a = base[mt][ntl];
        a = mfma16(pah, bl[ntl], a);
        a = mfma16(pal, bh[ntl], a);
        a = mfma16(pam, bm[ntl], a);
        a = mfma16(pah, bm[ntl], a);
        a = mfma16(pam, bh[ntl], a);
        a = mfma16(pah, bh[ntl], a);
        base[mt][ntl] = a;
      }
    }
  }

  // ---- recurrent state: lane owns rows row0+o and row0+16+o (wave-replicated) ----
  const float* idmp[2] = { idm + (size_t)(row0 + o) * (T * 12),
                           idm + (size_t)(row0 + 16 + o) * (T * 12) };
  const float* mrgp[2] = { merg + (size_t)(row0 + o) * (T * 3),
                           merg + (size_t)(row0 + 16 + o) * (T * 3) };
  float ego_v[2], ego_x[2], act[2] = {0.f, 0.f};

#pragma unroll 1
  for (int t = 0; t < T; ++t) {
    // ---- state + env features ----
    float xk[2][9];
#pragma unroll
    for (int mt = 0; mt < 2; ++mt) {
      const float* ip = idmp[mt] + t * 12;
      v4f s = *(const v4f*)ip;
      v2f f = *(const v2f*)(ip + 4);
      const float ex = ip[11];
      const float* mp = mrgp[mt] + t * 3;
      if (t == 0) { ego_v[mt] = s[0]; ego_x[mt] = s[3]; }
      else {
        ego_v[mt] += act[mt] * 0.1f;
        ego_x[mt] += ego_v[mt] * 0.1f + act[mt] * 0.005f;
      }
      xk[mt][0] = (ego_v[mt]                                     - mean[0]) * istd[0];
      xk[mt][1] = (s[1]                                          - mean[1]) * istd[1];
      xk[mt][2] = (ego_v[mt] - s[1]                              - mean[2]) * istd[2];
      xk[mt][3] = (f[0] - ego_x[mt]                              - mean[3]) * istd[3];
      xk[mt][4] = ((ego_v[mt] - s[2]) * ex                       - mean[4]) * istd[4];
      xk[mt][5] = ((f[1] - ego_x[mt]) * ex + (1.0f - ex) * 100.f - mean[5]) * istd[5];
      xk[mt][6] = mp[0]; xk[mt][7] = mp[1]; xk[mt][8] = mp[2];
    }

    // ---- env A-frags: A[m=o][k=8gq+j]; k<9 live, else 0 ----
    short8 eh[2], em[2];
#pragma unroll
    for (int mt = 0; mt < 2; ++mt) {
      uint32_t hi[8], mi[8];
#pragma unroll
      for (int j = 0; j < 8; ++j) {
        const float v = (gq == 0) ? xk[mt][j] : ((gq == 1 && j == 0) ? xk[mt][8] : 0.f);
        split2(v, hi[j], mi[j]);
      }
      eh[mt] = pack8(hi);
      em[mt] = pack8(mi);
    }

    // ---- layer 1 (3-term MFMA) -> relu -> packed write to sHc ----
#pragma unroll
    for (int mt = 0; mt < 2; ++mt)
#pragma unroll
      for (int ntl = 0; ntl < 2; ++ntl) {
        v4f a1 = base[mt][ntl];
        a1 = mfma16(eh[mt], envm[ntl], a1);
        a1 = mfma16(em[mt], envh[ntl], a1);
        a1 = mfma16(eh[mt], envh[ntl], a1);
#pragma unroll
        for (int r = 0; r < 4; ++r) {
          const float hv = fmaxf(a1[r], 0.f);
          uint32_t hi, mi; split2(hv, hi, mi);
          sHc[(mt * 16 + 4 * gq + r) * 132 + wave * 32 + ntl * 16 + o] = hi | (mi >> 16);
        }
      }
    __syncthreads();   // B1: all of h written

    // ---- layer 2: 3-term MFMA, A from sHc, B resident in registers ----
    v4f acc[2][2];
#pragma unroll
    for (int mt = 0; mt < 2; ++mt) {
      acc[mt][0] = (v4f){b2c0, b2c0, b2c0, b2c0};
      acc[mt][1] = (v4f){b2c1, b2c1, b2c1, b2c1};
    }
#pragma unroll
    for (int mt = 0; mt < 2; ++mt)
#pragma unroll
      for (int kt = 0; kt < 4; ++kt) {
        const uint32_t* src = &sHc[(mt * 16 + o) * 132 + kt * 32 + gq * 8];
        v4u q0 = *(const v4u*)src;
        v4u q1 = *(const v4u*)(src + 4);
        uint32_t u[8] = {q0[0], q0[1], q0[2], q0[3], q1[0], q1[1], q1[2], q1[3]};
        U8 uh, um;
#pragma unroll
        for (int d = 0; d < 4; ++d) {
          uh.u[d] = pack_hi16(u[2*d+1], u[2*d]);
          um.u[d] = pack_lo16(u[2*d+1], u[2*d]);
        }
        const short8 ah = uh.v, am = um.v;
#pragma unroll
        for (int ntl = 0; ntl < 2; ++ntl) {
          v4f a = acc[mt][ntl];
          a = mfma16(ah, w2m[kt * 2 + ntl], a);
          a = mfma16(am, w2h[kt * 2 + ntl], a);
          a = mfma16(ah, w2h[kt * 2 + ntl], a);
          acc[mt][ntl] = a;
        }
      }

    // ---- layer 3: per-wave partial dot, DPP row-sum, cross-wave via LDS ----
#pragma unroll
    for (int mt = 0; mt < 2; ++mt) {
      float part[4];
#pragma unroll
      for (int r = 0; r < 4; ++r)
        part[r] = fmaxf(acc[mt][0][r], 0.f) * w3c0 + fmaxf(acc[mt][1][r], 0.f) * w3c1;
#pragma unroll
      for (int r = 0; r < 4; ++r) part[r] = row_sum16(part[r]);
      if (o == 0) {
#pragma unroll
        for (int r = 0; r < 4; ++r)
          actP[(mt * 16 + 4 * gq + r) * 4 + wave] = part[r];
      }
    }
    __syncthreads();   // B2: partials written; also protects sHc WAR for t+1

#pragma unroll
    for (int mt = 0; mt < 2; ++mt) {
      v4f ap = *(const v4f*)&actP[(mt * 16 + o) * 4];
      act[mt] = ap[0] + ap[1] + ap[2] + ap[3] + b3v;
    }

    if (wave == 0 && gq == 0) {
      out[(size_t)(row0 + o)      * T + t] = act[0];
      out[(size_t)(row0 + 16 + o) * T + t] = act[1];
    }
  }
}

}  // namespace

extern "C" void kernel_launch(void* const* d_in, const int* in_sizes, int n_in,
                              void* d_out, int out_size, void* d_ws, size_t ws_size,
                              hipStream_t stream) {
  const float* proj  = (const float*)d_in[0];
  const float* idm   = (const float*)d_in[1];
  const float* merg  = (const float*)d_in[2];
  const float* W1    = (const float*)d_in[3];
  const float* b1    = (const float*)d_in[4];
  const float* W2    = (const float*)d_in[5];
  const float* b2    = (const float*)d_in[6];
  const float* W3    = (const float*)d_in[7];
  const float* b3    = (const float*)d_in[8];
  const float* smean = (const float*)d_in[9];
  const float* svar  = (const float*)d_in[10];
  // d_in[11] = rollout_len (fixed 50)

  dim3 grid(NB / BLK_ROWS);   // 1024 blocks; 2 blocks/CU co-resident, 2 rounds
  dim3 block(NTHREADS);       // 256 threads = 4 waves (each owns a 32-col N-slice)
  hipLaunchKernelGGL(fwdsim5, grid, block, 0, stream,
                     proj, idm, merg, W1, b1, W2, b2, W3, b3, smean, svar,
                     (float*)d_out);
}